// Round 6
// baseline (26.099 us; speedup 1.0000x reference)
//
#include <hip/hip_runtime.h>
#include <math.h>
#include <stdint.h>

// ---------------------------------------------------------------------------
// VNFrameEstimator, split lean kernels:
//  K1 (streaming, f32-only): 16 lanes/batch, per-lane contiguous float3
//     (dwordx3) loads -> 192B contiguous per 16-lane group per instruction
//     (TA-friendly, ~8 lines/wave-instr). Normalize (rsq + 1 NR) + moment
//     accumulate in f32, 16-lane DPP rotate-reduce, 9 f32 moments -> ws SoA.
//     No f64 => low VGPR => high occupancy.
//  K2 (eigensolve): 1 thread/batch, all threads active; f64 3x3 Jacobi,
//     4 sweeps (12 rotations, converged), sort, sign-fix, cross, write frame.
// ---------------------------------------------------------------------------

#define BLOCK 256
#define ITERS 2
#define BPB   32   // batches per block in K1 (4 waves * 4 groups * 2 iters)

// f32 rotate within the 16-lane DPP row (pure VALU). CTRL: ROW_ROR:N = 0x120|N.
template <int CTRL>
__device__ __forceinline__ float ror16_f32(float v) {
    union { float f; int i; } u, r;
    u.f = v;
    r.i = __builtin_amdgcn_mov_dpp(u.i, CTRL, 0xF, 0xF, true);
    return r.f;
}

// 1/sqrt(x), ~1e-15 rel err (f32 seed + 2 f64 NR steps).
__device__ __forceinline__ double fast_rsqrt2(double x) {
    double r = (double)__builtin_amdgcn_rsqf((float)x);
    double h = -0.5 * x;
    r = r * fma(h, r * r, 1.5);
    r = r * fma(h, r * r, 1.5);
    return r;
}
// 1/x, ~1e-15 rel err (2 NR steps). |x| f32-representable (guarded by caller).
__device__ __forceinline__ double fast_rcp(double x) {
    double r = (double)__builtin_amdgcn_rcpf((float)x);
    r = r * fma(-x, r, 2.0);
    r = r * fma(-x, r, 2.0);
    return r;
}

// ------------------------------- Kernel 1 ----------------------------------
__global__ __launch_bounds__(BLOCK) void vn_phase1(
    const float* __restrict__ vf, float* __restrict__ wsm, int B) {
    const int tid  = threadIdx.x;
    const int wave = tid >> 6;
    const int lane = tid & 63;
    const int g    = lane >> 4;   // batch group within wave
    const int sub  = lane & 15;   // lane within 16-group

    const int blockBase = blockIdx.x * BPB;

#pragma unroll
    for (int it = 0; it < ITERS; ++it) {
        const int bslot = wave * (4 * ITERS) + it * 4 + g;
        const int b = blockBase + bslot;
        if (b < B) {
            const float* base = vf + (size_t)b * 384;

            float m[9];
#pragma unroll
            for (int k = 0; k < 9; ++k) m[k] = 0.0f;

            // lane sub handles vectors {16j + sub}: per-instruction the 16
            // lanes read 192B contiguous (float3, dwordx3).
#pragma unroll
            for (int j = 0; j < 8; ++j) {
                const float3 v =
                    *reinterpret_cast<const float3*>(base + (16 * j + sub) * 3);
                float fx = v.x, fy = v.y, fz = v.z;
                float n2 = fmaf(fx, fx, fmaf(fy, fy, fz * fz));
                float r = __builtin_amdgcn_rsqf(n2);
                r = r * fmaf(-0.5f * n2, r * r, 1.5f);   // 1 NR, ~1 ulp
                float inv = (n2 > 1e-24f) ? r : 1e12f;
                float x = fx * inv;
                float y = fy * inv;
                float z = fz * inv;
                m[0] = fmaf(x, x, m[0]);
                m[1] = fmaf(x, y, m[1]);
                m[2] = fmaf(x, z, m[2]);
                m[3] = fmaf(y, y, m[3]);
                m[4] = fmaf(y, z, m[4]);
                m[5] = fmaf(z, z, m[5]);
                m[6] += x; m[7] += y; m[8] += z;
            }

            // 16-lane rotate-reduce on the VALU pipe (DPP row_ror 1,2,4,8)
#pragma unroll
            for (int k = 0; k < 9; ++k) m[k] += ror16_f32<0x121>(m[k]);
#pragma unroll
            for (int k = 0; k < 9; ++k) m[k] += ror16_f32<0x122>(m[k]);
#pragma unroll
            for (int k = 0; k < 9; ++k) m[k] += ror16_f32<0x124>(m[k]);
#pragma unroll
            for (int k = 0; k < 9; ++k) m[k] += ror16_f32<0x128>(m[k]);

            if (sub == 0) {
#pragma unroll
                for (int k = 0; k < 9; ++k) wsm[(size_t)k * B + b] = m[k];
            }
        }
    }
}

// ------------------------------- Kernel 2 ----------------------------------
template <int P, int Q, int R>
__device__ __forceinline__ void jrot(double (&A)[3][3], double (&V)[3][3]) {
    double apq = A[P][Q];
    if (fabs(apq) > 1e-18) {
        double theta = (A[Q][Q] - A[P][P]) * 0.5 * fast_rcp(apq);
        double q = fma(theta, theta, 1.0);
        double sq = (q < 1e37) ? q * fast_rsqrt2(q) : fabs(theta); // sqrt(q)
        double t = fast_rcp(fabs(theta) + sq);
        if (theta < 0.0) t = -t;
        double c = fast_rsqrt2(fma(t, t, 1.0));
        double s = t * c;
        double apq_t = t * apq;
        A[P][P] = A[P][P] - apq_t;
        A[Q][Q] = A[Q][Q] + apq_t;
        A[P][Q] = 0.0;
        A[Q][P] = 0.0;
        double apr = A[P][R], aqr = A[Q][R];
        A[P][R] = c * apr - s * aqr; A[R][P] = A[P][R];
        A[Q][R] = s * apr + c * aqr; A[R][Q] = A[Q][R];
#pragma unroll
        for (int i = 0; i < 3; ++i) {
            double vip = V[i][P], viq = V[i][Q];
            V[i][P] = c * vip - s * viq;
            V[i][Q] = s * vip + c * viq;
        }
    }
}

__global__ __launch_bounds__(256) void vn_phase2(
    const float* __restrict__ wsm, float* __restrict__ out, int B) {
    const int b = blockIdx.x * 256 + threadIdx.x;
    if (b >= B) return;

    double m[9];
#pragma unroll
    for (int k = 0; k < 9; ++k) m[k] = (double)wsm[(size_t)k * B + b];

    double A[3][3], V[3][3];
    A[0][0] = m[0] + (double)1e-05f;
    A[0][1] = m[1]; A[1][0] = m[1];
    A[0][2] = m[2]; A[2][0] = m[2];
    A[1][1] = m[3] + (double)2e-05f;
    A[1][2] = m[4]; A[2][1] = m[4];
    A[2][2] = m[5] + (double)3e-05f;
#pragma unroll
    for (int i = 0; i < 3; ++i)
#pragma unroll
        for (int j = 0; j < 3; ++j) V[i][j] = (i == j) ? 1.0 : 0.0;

#pragma unroll
    for (int sweep = 0; sweep < 4; ++sweep) {   // 12 rotations: converged
        jrot<0, 1, 2>(A, V);
        jrot<0, 2, 1>(A, V);
        jrot<1, 2, 0>(A, V);
    }

    double e0 = A[0][0], e1 = A[1][1], e2 = A[2][2];
    double c0x = V[0][0], c0y = V[1][0], c0z = V[2][0];
    double c1x = V[0][1], c1y = V[1][1], c1z = V[2][1];
    double c2x = V[0][2], c2y = V[1][2], c2z = V[2][2];

#define CSWAP(ea, eb, ax, ay, az, bx, by, bz)                         \
    if (ea > eb) {                                                    \
        double t_;                                                    \
        t_ = ea; ea = eb; eb = t_;                                    \
        t_ = ax; ax = bx; bx = t_;                                    \
        t_ = ay; ay = by; by = t_;                                    \
        t_ = az; az = bz; bz = t_;                                    \
    }
    CSWAP(e0, e1, c0x, c0y, c0z, c1x, c1y, c1z)
    CSWAP(e1, e2, c1x, c1y, c1z, c2x, c2y, c2z)
    CSWAP(e0, e1, c0x, c0y, c0z, c1x, c1y, c1z)
#undef CSWAP

    double s0 = m[6], s1 = m[7], s2 = m[8];
    double d1 = s0 * c0x + s1 * c0y + s2 * c0z;
    double f1 = (d1 < 0.0) ? -1.0 : 1.0;
    c0x *= f1; c0y *= f1; c0z *= f1;
    double d2 = s0 * c1x + s1 * c1y + s2 * c1z;
    double f2 = (d2 < 0.0) ? -1.0 : 1.0;
    c1x *= f2; c1y *= f2; c1z *= f2;

    double v3x = c0y * c1z - c0z * c1y;
    double v3y = c0z * c1x - c0x * c1z;
    double v3z = c0x * c1y - c0y * c1x;

    float* o = out + (size_t)b * 9;
    o[0] = (float)c0x; o[1] = (float)c1x; o[2] = (float)v3x;
    o[3] = (float)c0y; o[4] = (float)c1y; o[5] = (float)v3y;
    o[6] = (float)c0z; o[7] = (float)c1z; o[8] = (float)v3z;
}

extern "C" void kernel_launch(void* const* d_in, const int* in_sizes, int n_in,
                              void* d_out, int out_size, void* d_ws, size_t ws_size,
                              hipStream_t stream) {
    const float* vf = (const float*)d_in[0];
    float* out = (float*)d_out;
    float* wsm = (float*)d_ws;   // 9 * B floats (SoA), ~2.4 MB
    const int B = in_sizes[0] / 384;  // 128 vectors * 3 components
    const int grid1 = (B + BPB - 1) / BPB;
    vn_phase1<<<dim3(grid1), dim3(BLOCK), 0, stream>>>(vf, wsm, B);
    const int grid2 = (B + 255) / 256;
    vn_phase2<<<dim3(grid2), dim3(256), 0, stream>>>(wsm, out, B);
}

// Round 7
// 24.091 us; speedup vs baseline: 1.0834x; 1.0834x over previous
//
#include <hip/hip_runtime.h>
#include <math.h>
#include <stdint.h>

// ---------------------------------------------------------------------------
// VNFrameEstimator, fully-f32 single fused kernel:
//  - 16 lanes/batch, per-lane contiguous 96B (6x float4) loads; TWO batches'
//    loads issued back-to-back (12 dwordx4 in flight) before any use.
//  - normalize with raw v_rsq_f32 (~1e-6 rel, harmless vs 2e-2/bf16 check),
//    f32 moment accumulate, 16-lane DPP row_ror rotate-reduce.
//  - fused tail: 1 thread/batch f32 3x3 Jacobi (libm-free, NR-refined rcp/
//    rsqrt), sort, sign-fix, cross, write frame. No f64 anywhere, no ws.
// ---------------------------------------------------------------------------

#define BLOCK 256
#define BPB   32   // 4 waves * 4 groups * 2 batches-per-group

// f32 rotate within the 16-lane DPP row (pure VALU). CTRL: ROW_ROR:N = 0x120|N.
template <int CTRL>
__device__ __forceinline__ float ror16_f32(float v) {
    union { float f; int i; } u, r;
    u.f = v;
    r.i = __builtin_amdgcn_mov_dpp(u.i, CTRL, 0xF, 0xF, true);
    return r.f;
}

// f32 1/sqrt, ~1 ulp (HW seed + 1 NR)
__device__ __forceinline__ float frsqrt(float x) {
    float r = __builtin_amdgcn_rsqf(x);
    return r * fmaf(-0.5f * x, r * r, 1.5f);
}
// f32 1/x, ~1 ulp (HW seed + 1 NR)
__device__ __forceinline__ float frcp(float x) {
    float r = __builtin_amdgcn_rcpf(x);
    return r * fmaf(-x, r, 2.0f);
}

// One f32 Jacobi rotation zeroing A[P][Q]; R is the remaining index.
template <int P, int Q, int R>
__device__ __forceinline__ void jrot(float (&A)[3][3], float (&V)[3][3]) {
    float apq = A[P][Q];
    if (fabsf(apq) > 1e-12f) {
        float theta = (A[Q][Q] - A[P][P]) * 0.5f * frcp(apq);
        float q = fmaf(theta, theta, 1.0f);
        float sq = q * frsqrt(q);                  // sqrt(theta^2+1)
        float t = frcp(fabsf(theta) + sq);
        if (theta < 0.0f) t = -t;
        float c = frsqrt(fmaf(t, t, 1.0f));
        float s = t * c;
        float apq_t = t * apq;
        A[P][P] = A[P][P] - apq_t;
        A[Q][Q] = A[Q][Q] + apq_t;
        A[P][Q] = 0.0f;
        A[Q][P] = 0.0f;
        float apr = A[P][R], aqr = A[Q][R];
        A[P][R] = fmaf(c, apr, -s * aqr); A[R][P] = A[P][R];
        A[Q][R] = fmaf(s, apr,  c * aqr); A[R][Q] = A[Q][R];
#pragma unroll
        for (int i = 0; i < 3; ++i) {
            float vip = V[i][P], viq = V[i][Q];
            V[i][P] = fmaf(c, vip, -s * viq);
            V[i][Q] = fmaf(s, vip,  c * viq);
        }
    }
}

// accumulate 8 vectors (24 floats) into 9 f32 moments
__device__ __forceinline__ void accum8(const float4 (&q)[6], float (&m)[9]) {
    float f[24];
#pragma unroll
    for (int i = 0; i < 6; ++i) {
        f[4 * i + 0] = q[i].x; f[4 * i + 1] = q[i].y;
        f[4 * i + 2] = q[i].z; f[4 * i + 3] = q[i].w;
    }
#pragma unroll
    for (int k = 0; k < 8; ++k) {
        float fx = f[3 * k + 0];
        float fy = f[3 * k + 1];
        float fz = f[3 * k + 2];
        float n2 = fmaf(fx, fx, fmaf(fy, fy, fz * fz));
        float r = __builtin_amdgcn_rsqf(n2);       // ~1e-6 rel, sufficient
        float inv = (n2 > 1e-24f) ? r : 1e12f;
        float x = fx * inv;
        float y = fy * inv;
        float z = fz * inv;
        m[0] = fmaf(x, x, m[0]);
        m[1] = fmaf(x, y, m[1]);
        m[2] = fmaf(x, z, m[2]);
        m[3] = fmaf(y, y, m[3]);
        m[4] = fmaf(y, z, m[4]);
        m[5] = fmaf(z, z, m[5]);
        m[6] += x; m[7] += y; m[8] += z;
    }
}

__device__ __forceinline__ void reduce16(float (&m)[9]) {
#pragma unroll
    for (int k = 0; k < 9; ++k) m[k] += ror16_f32<0x121>(m[k]);
#pragma unroll
    for (int k = 0; k < 9; ++k) m[k] += ror16_f32<0x122>(m[k]);
#pragma unroll
    for (int k = 0; k < 9; ++k) m[k] += ror16_f32<0x124>(m[k]);
#pragma unroll
    for (int k = 0; k < 9; ++k) m[k] += ror16_f32<0x128>(m[k]);
}

__global__ __launch_bounds__(BLOCK) void vn_fused(
    const float* __restrict__ vf, float* __restrict__ out, int B) {
    __shared__ float sA[BPB][9];

    const int tid  = threadIdx.x;
    const int wave = tid >> 6;
    const int lane = tid & 63;
    const int g    = lane >> 4;   // group within wave
    const int sub  = lane & 15;   // lane within 16-group

    const int blockBase = blockIdx.x * BPB;
    const int slotA = wave * 8 + g;       // batches 0..3 of this wave's 8
    const int slotB = wave * 8 + 4 + g;   // batches 4..7
    const int bA = blockBase + slotA;
    const int bB = blockBase + slotB;

    // issue ALL loads (12 dwordx4/lane) before any use
    float4 qa[6], qb[6];
    if (bA < B) {
        const float4* pa =
            reinterpret_cast<const float4*>(vf + (size_t)bA * 384 + sub * 24);
#pragma unroll
        for (int i = 0; i < 6; ++i) qa[i] = pa[i];
    }
    if (bB < B) {
        const float4* pb =
            reinterpret_cast<const float4*>(vf + (size_t)bB * 384 + sub * 24);
#pragma unroll
        for (int i = 0; i < 6; ++i) qb[i] = pb[i];
    }

    if (bA < B) {
        float m[9];
#pragma unroll
        for (int k = 0; k < 9; ++k) m[k] = 0.0f;
        accum8(qa, m);
        reduce16(m);
        if (sub == 0) {
#pragma unroll
            for (int k = 0; k < 9; ++k) sA[slotA][k] = m[k];
        }
    }
    if (bB < B) {
        float m[9];
#pragma unroll
        for (int k = 0; k < 9; ++k) m[k] = 0.0f;
        accum8(qb, m);
        reduce16(m);
        if (sub == 0) {
#pragma unroll
            for (int k = 0; k < 9; ++k) sA[slotB][k] = m[k];
        }
    }

    __syncthreads();

    // ---- fused tail: 1 thread per batch, f32 3x3 Jacobi eigensolve ----
    if (tid < BPB) {
        const int b = blockBase + tid;
        if (b < B) {
            float m[9];
#pragma unroll
            for (int k = 0; k < 9; ++k) m[k] = sA[tid][k];

            float A[3][3], V[3][3];
            A[0][0] = m[0] + 1e-05f;
            A[0][1] = m[1]; A[1][0] = m[1];
            A[0][2] = m[2]; A[2][0] = m[2];
            A[1][1] = m[3] + 2e-05f;
            A[1][2] = m[4]; A[2][1] = m[4];
            A[2][2] = m[5] + 3e-05f;
#pragma unroll
            for (int i = 0; i < 3; ++i)
#pragma unroll
                for (int j = 0; j < 3; ++j) V[i][j] = (i == j) ? 1.0f : 0.0f;

#pragma unroll
            for (int sweep = 0; sweep < 6; ++sweep) {
                jrot<0, 1, 2>(A, V);
                jrot<0, 2, 1>(A, V);
                jrot<1, 2, 0>(A, V);
            }

            float e0 = A[0][0], e1 = A[1][1], e2 = A[2][2];
            float c0x = V[0][0], c0y = V[1][0], c0z = V[2][0];
            float c1x = V[0][1], c1y = V[1][1], c1z = V[2][1];
            float c2x = V[0][2], c2y = V[1][2], c2z = V[2][2];

#define CSWAP(ea, eb, ax, ay, az, bx, by, bz)                         \
            if (ea > eb) {                                            \
                float t_;                                             \
                t_ = ea; ea = eb; eb = t_;                            \
                t_ = ax; ax = bx; bx = t_;                            \
                t_ = ay; ay = by; by = t_;                            \
                t_ = az; az = bz; bz = t_;                            \
            }
            CSWAP(e0, e1, c0x, c0y, c0z, c1x, c1y, c1z)
            CSWAP(e1, e2, c1x, c1y, c1z, c2x, c2y, c2z)
            CSWAP(e0, e1, c0x, c0y, c0z, c1x, c1y, c1z)
#undef CSWAP

            float s0 = m[6], s1 = m[7], s2 = m[8];
            float d1 = s0 * c0x + s1 * c0y + s2 * c0z;
            float f1 = (d1 < 0.0f) ? -1.0f : 1.0f;
            c0x *= f1; c0y *= f1; c0z *= f1;
            float d2 = s0 * c1x + s1 * c1y + s2 * c1z;
            float f2 = (d2 < 0.0f) ? -1.0f : 1.0f;
            c1x *= f2; c1y *= f2; c1z *= f2;

            float v3x = c0y * c1z - c0z * c1y;
            float v3y = c0z * c1x - c0x * c1z;
            float v3z = c0x * c1y - c0y * c1x;

            float* o = out + (size_t)b * 9;
            o[0] = c0x; o[1] = c1x; o[2] = v3x;
            o[3] = c0y; o[4] = c1y; o[5] = v3y;
            o[6] = c0z; o[7] = c1z; o[8] = v3z;
        }
    }
}

extern "C" void kernel_launch(void* const* d_in, const int* in_sizes, int n_in,
                              void* d_out, int out_size, void* d_ws, size_t ws_size,
                              hipStream_t stream) {
    const float* vf = (const float*)d_in[0];
    float* out = (float*)d_out;
    const int B = in_sizes[0] / 384;   // 128 vectors * 3 components
    const int grid = (B + BPB - 1) / BPB;
    vn_fused<<<dim3(grid), dim3(BLOCK), 0, stream>>>(vf, out, B);
}